// Round 2
// baseline (378.511 us; speedup 1.0000x reference)
//
#include <hip/hip_runtime.h>
#include <cstdint>
#include <cstddef>

// ---------------------------------------------------------------------------
// cross_attention: b=8, c=32, 252x252, ws=8 -> padded 256x256.
// tokens l=(i1,j1) in 32x32, features d'=(i0*256 + j0*32 + c) in 2048.
// Pipeline (R7): pack_qk_fused (norms computed in-block; raw bf16 pack +
//   in-place scale)  ->  pack_v (raw bf16 Vt + fused sum-of-squares -> svsum
//   via 4-lane reduce + atomicAdd; sv_kernel ELIMINATED, -32 MB HBM)  ->
//   S = Qh Kh^T * 2048^-0.5 -> softmax -> Ot = (rsqrt(svsum).*Vt) P^T scatter.
// Streaming kernels cap ~2.6 TB/s on this platform regardless of shape
// (R2 vs R5 evidence), so bytes are the only lever.
// ---------------------------------------------------------------------------

typedef __bf16 bf16x8 __attribute__((ext_vector_type(8)));
typedef float  f32x4  __attribute__((ext_vector_type(4)));

__device__ __forceinline__ unsigned int f2bf(float f) {
  unsigned int u = __builtin_bit_cast(unsigned int, f);
  u += 0x7FFFu + ((u >> 16) & 1u);   // round-to-nearest-even
  return u >> 16;
}
__device__ __forceinline__ float bf2f(unsigned int h) {
  return __builtin_bit_cast(float, h << 16);
}

__device__ __forceinline__ void load_lds16(const void* g, void* l) {
  __builtin_amdgcn_global_load_lds(
      (const __attribute__((address_space(1))) void*)g,
      (__attribute__((address_space(3))) void*)l, 16, 0, 0);
}

// ---------------------------------------------------------------------------
// Kernel 1: fused norm+pack for Q,K. Block = (t, b, i0, j0g): owns the
// 32c x 32h x 64w strip (w in [j0g*64, j0g*64+64)) = windows (i0, j0g*2+{0,1}).
// Loop i1: stage raw fp32 row-slice in tf[32][65] (<=2-way banks), gather raw
// bf16 uint4 -> Qh/Kh (128B contiguous, lines fully owned), accumulating
// weighted squares for the 64 (c,j0l) window norms. Then reduce -> scales,
// and phase C rescales the block's own 1024x64 output region in place
// (L2-hot round trip). Reflect pad by weights (247..250 x2, >=252 -> 0).
// ---------------------------------------------------------------------------
__global__ __launch_bounds__(256)
void pack_qk_fused(const float* __restrict__ q, const float* __restrict__ k,
                   unsigned short* __restrict__ Qh,
                   unsigned short* __restrict__ Kh) {
  int bx  = blockIdx.x;          // grid 512
  int t   = bx >> 8;             // 0..1
  int b   = (bx >> 5) & 7;
  int i0  = (bx >> 2) & 7;
  int j0g = bx & 3;
  const float* xb = (t ? k : q) + (size_t)b * 32 * 63504;

  __shared__ float tf[32 * 65];    // [c][pos 0..63], stride 65 -> bank = c+pos
  __shared__ float red[512];
  __shared__ float sclt[64];       // [c*2 + j0l]

  int tid = threadIdx.x;
  int ch  = tid & 15;              // 16B chunk within 64-w slice
  int c2  = tid >> 4;              // c = c2, c2+16

  int wbase = j0g * 64 + ch * 4;
  float we[4];
  #pragma unroll
  for (int e = 0; e < 4; e++) {
    int w = wbase + e;
    we[e] = (w >= 252) ? 0.f : (((unsigned)(w - 247) <= 3u) ? 2.f : 1.f);
  }
  bool tail = (wbase == 252);      // only j0g==3, ch==15

  float pa = 0.f, pb = 0.f;        // window sums for c2 / c2+16 (j0l fixed)
  unsigned short* X = (t ? Kh : Qh) + (size_t)b * 1024 * 2048;

  int gsub = tid & 7;              // gather: d' octet within 64
  int gj1  = tid >> 3;
  int gjl  = gsub >> 2;
  int gc0  = (gsub & 3) * 8;

  for (int i1 = 0; i1 < 32; i1++) {
    int h  = i0 * 32 + i1;
    int hs = (h < 252) ? h : 502 - h;
    float rw = (h >= 252) ? 0.f : (((unsigned)(h - 247) <= 3u) ? 2.f : 1.f);
    const float* rowp = xb + (size_t)hs * 252;

    #pragma unroll
    for (int it = 0; it < 2; it++) {
      int c = c2 + it * 16;
      const float* src = rowp + (size_t)c * 63504;
      float4 vv;
      if (!tail) {
        vv = *(const float4*)&src[wbase];
      } else {  // w 252..255 mirror to 250,249,248,247
        vv.x = src[250]; vv.y = src[249]; vv.z = src[248]; vv.w = src[247];
      }
      float s = rw * (we[0] * vv.x * vv.x + we[1] * vv.y * vv.y +
                      we[2] * vv.z * vv.z + we[3] * vv.w * vv.w);
      if (it == 0) pa += s; else pb += s;
      float* dst = &tf[c * 65 + ch * 4];
      dst[0] = vv.x; dst[1] = vv.y; dst[2] = vv.z; dst[3] = vv.w;
    }
    __syncthreads();
    {
      int pos = gjl * 32 + gj1;
      unsigned int ov[4];
      #pragma unroll
      for (int m = 0; m < 4; m++) {
        unsigned int lo = f2bf(tf[(gc0 + 2 * m)     * 65 + pos]);
        unsigned int hi = f2bf(tf[(gc0 + 2 * m + 1) * 65 + pos]);
        ov[m] = lo | (hi << 16);
      }
      int l = i1 * 32 + gj1;
      uint4 o4; o4.x = ov[0]; o4.y = ov[1]; o4.z = ov[2]; o4.w = ov[3];
      *(uint4*)&X[(size_t)l * 2048 + i0 * 256 + j0g * 64 + gsub * 8] = o4;
    }
    __syncthreads();
  }

  // reduce partials -> 64 scales
  red[tid] = pa; red[256 + tid] = pb;
  __syncthreads();
  if (tid < 64) {
    int c = tid & 31, jl = tid >> 5;
    int base = (c & 15) * 16 + jl * 8 + ((c >= 16) ? 256 : 0);
    float s = 0.f;
    #pragma unroll
    for (int u = 0; u < 8; u++) s += red[base + u];
    sclt[c * 2 + jl] = 1.f / fmaxf(sqrtf(s), 1e-12f);
  }
  __syncthreads();

  // phase C: in-place scale of the block's 1024 x 64 d' region (L2-hot)
  {
    float sc[8];
    #pragma unroll
    for (int m = 0; m < 8; m++) sc[m] = sclt[(gc0 + m) * 2 + gjl];
    unsigned short* basep = &X[i0 * 256 + j0g * 64 + gsub * 8];
    int lb = tid >> 3;
    #pragma unroll 4
    for (int it = 0; it < 32; it++) {
      size_t off = (size_t)(it * 32 + lb) * 2048;
      uint4 u = *(uint4*)&basep[off];
      uint4 o;
      o.x = f2bf(bf2f(u.x & 0xFFFF) * sc[0]) | (f2bf(bf2f(u.x >> 16) * sc[1]) << 16);
      o.y = f2bf(bf2f(u.y & 0xFFFF) * sc[2]) | (f2bf(bf2f(u.y >> 16) * sc[3]) << 16);
      o.z = f2bf(bf2f(u.z & 0xFFFF) * sc[4]) | (f2bf(bf2f(u.z >> 16) * sc[5]) << 16);
      o.w = f2bf(bf2f(u.w & 0xFFFF) * sc[6]) | (f2bf(bf2f(u.w >> 16) * sc[7]) << 16);
      *(uint4*)&basep[off] = o;
    }
  }
}

// ---------------------------------------------------------------------------
// Kernel 2: pack V to bf16 Vt[d'][l] — RAW (scale folded into gemm2), no LDS.
// Fused: sum-of-squares per (b, d') row accumulated into svsum via 4-lane
// shfl reduce + one atomicAdd per (c, j0) per block (32 atomics/address
// total — negligible contention). Norm is over the PADDED token set
// (mirror duplicates included), matching the reference which pads before
// normalize. svsum must be zeroed before launch (hipMemsetAsync).
// ---------------------------------------------------------------------------
__global__ void pack_v_kernel(const float* __restrict__ v,
                              unsigned short* __restrict__ Vt,
                              float* __restrict__ svsum) {
  int bx = blockIdx.x;
  int b  = bx >> 8;
  int i0 = (bx >> 5) & 7;
  int i1 = bx & 31;
  int h  = i0 * 32 + i1;
  int hs = (h < 252) ? h : 502 - h;
  const float* src = v + (size_t)b * 32 * 63504 + (size_t)hs * 252;
  unsigned short* dst = Vt + (size_t)b * 2048 * 1024
                           + (size_t)(i0 * 256) * 1024 + i1 * 32;

  int tid = threadIdx.x;
  int j1c = tid & 3;
  int c   = (tid >> 2) & 31;
  int j0g = tid >> 7;          // 0..1
  const float* s = src + (size_t)c * 63504;

  float psum[4];

  #pragma unroll
  for (int jj = 0; jj < 4; jj++) {
    int j0 = j0g * 4 + jj;
    int w0 = j0 * 32 + j1c * 8;
    float f0, f1, f2, f3, f4, f5, f6, f7;
    if (w0 + 8 <= 252) {
      float4 a = *(const float4*)&s[w0];
      float4 bq = *(const float4*)&s[w0 + 4];
      f0 = a.x; f1 = a.y; f2 = a.z; f3 = a.w;
      f4 = bq.x; f5 = bq.y; f6 = bq.z; f7 = bq.w;
    } else {  // w0==248: cols 248..255 -> 248,249,250,251,250,249,248,247
      float4 a = *(const float4*)&s[244];
      float4 bq = *(const float4*)&s[248];
      f0 = bq.x; f1 = bq.y; f2 = bq.z; f3 = bq.w;
      f4 = bq.z; f5 = bq.y; f6 = bq.x; f7 = a.w;
    }
    psum[jj] = f0*f0 + f1*f1 + f2*f2 + f3*f3 + f4*f4 + f5*f5 + f6*f6 + f7*f7;
    uint4 o;
    o.x = f2bf(f0) | (f2bf(f1) << 16);
    o.y = f2bf(f2) | (f2bf(f3) << 16);
    o.z = f2bf(f4) | (f2bf(f5) << 16);
    o.w = f2bf(f6) | (f2bf(f7) << 16);
    *(uint4*)&dst[(size_t)(j0 * 32 + c) * 1024 + j1c * 8] = o;
  }

  // 4-lane (j1c) reduce -> one atomicAdd per (c, j0) per block
  #pragma unroll
  for (int jj = 0; jj < 4; jj++) {
    float ssum = psum[jj];
    ssum += __shfl_down(ssum, 2, 4);
    ssum += __shfl_down(ssum, 1, 4);
    if (j1c == 0) {
      int j0 = j0g * 4 + jj;
      atomicAdd(&svsum[(size_t)b * 2048 + i0 * 256 + j0 * 32 + c], ssum);
    }
  }
}

// ---------------------------------------------------------------------------
// GEMM NT: C[M][N] = A[M][K] * B[N][K]^T, bf16 in, fp32 acc.
// 1D grid, decode: b = flat&7 (XCD affinity), m = (flat>>3)>>3, n = flat&7
// of the remainder -> successive same-XCD blocks reuse the A-tile in L2.
// MODE 0: store bf16 S * scale.  MODE 1: acc *= rsqrt(svsum[row]), scatter
// fp32 + crop.
// ---------------------------------------------------------------------------
template <int MODE>
__global__ __launch_bounds__(256, 4)
void gemm_nt(const unsigned short* __restrict__ A,
             const unsigned short* __restrict__ B,
             int K, int Asb, int Bsb, void* __restrict__ Cout, float scale,
             const float* __restrict__ sv) {
  __shared__ unsigned short lA[128 * 64];
  __shared__ unsigned short lB[128 * 64];
  __shared__ float svb[(MODE == 1) ? 128 : 1];

  const int flat = blockIdx.x;
  const int zz   = flat & 7;
  const int rr   = flat >> 3;
  const int my   = rr >> 3;
  const int nx   = rr & 7;

  const int tid  = threadIdx.x;
  const int lane = tid & 63;
  const int wave = tid >> 6;
  const int ln15 = lane & 15;
  const int q4   = lane >> 4;
  const int wm   = wave >> 1;
  const int wn   = wave & 1;
  const int m0   = my * 128;
  const int n0   = nx * 128;
  const unsigned short* Ab = A + (size_t)zz * Asb;
  const unsigned short* Bb = B + (size_t)zz * Bsb;

  if (MODE == 1 && tid < 128)
    svb[tid] = 1.f / fmaxf(sqrtf(sv[(size_t)zz * 2048 + m0 + tid]), 1e-12f);

  const int srow = lane >> 3;
  const int kcp  = lane & 7;
  const int kcl  = kcp ^ srow;      // xor-swizzled source chunk

  f32x4 acc[4][4] = {};

  for (int k0 = 0; k0 < K; k0 += 64) {
    #pragma unroll
    for (int r = 0; r < 4; r++) {
      int rowg = wave * 32 + r * 8;
      int row  = rowg + srow;
      load_lds16(&Ab[(size_t)(m0 + row) * K + k0 + kcl * 8], &lA[rowg * 64]);
      load_lds16(&Bb[(size_t)(n0 + row) * K + k0 + kcl * 8], &lB[rowg * 64]);
    }
    __syncthreads();
    #pragma unroll
    for (int kk = 0; kk < 2; kk++) {
      bf16x8 af[4], bfr[4];
      #pragma unroll
      for (int mt = 0; mt < 4; mt++) {
        int row = wm * 64 + mt * 16 + ln15;
        int pc  = (kk * 4 + q4) ^ (row & 7);
        af[mt] = *(const bf16x8*)&lA[row * 64 + pc * 8];
      }
      #pragma unroll
      for (int nt = 0; nt < 4; nt++) {
        int row = wn * 64 + nt * 16 + ln15;
        int pc  = (kk * 4 + q4) ^ (row & 7);
        bfr[nt] = *(const bf16x8*)&lB[row * 64 + pc * 8];
      }
      #pragma unroll
      for (int mt = 0; mt < 4; mt++)
        #pragma unroll
        for (int nt = 0; nt < 4; nt++)
          acc[mt][nt] = __builtin_amdgcn_mfma_f32_16x16x32_bf16(
              af[mt], bfr[nt], acc[mt][nt], 0, 0, 0);
    }
    __syncthreads();
  }

  if (MODE == 0) {
    unsigned short* Sb = (unsigned short*)Cout + (size_t)zz * 1024 * 1024;
    #pragma unroll
    for (int mt = 0; mt < 4; mt++) {
      #pragma unroll
      for (int nt = 0; nt < 4; nt++) {
        int col = n0 + wn * 64 + nt * 16 + ln15;
        #pragma unroll
        for (int rg = 0; rg < 4; rg++) {
          int rowi = m0 + wm * 64 + mt * 16 + q4 * 4 + rg;
          Sb[(size_t)rowi * 1024 + col] = (unsigned short)f2bf(acc[mt][nt][rg] * scale);
        }
      }
    }
  } else {
    float* Ob = (float*)Cout;
    #pragma unroll
    for (int mt = 0; mt < 4; mt++) {
      #pragma unroll
      for (int nt = 0; nt < 4; nt++) {
        int l  = n0 + wn * 64 + nt * 16 + ln15;
        int i1 = l >> 5, j1 = l & 31;
        #pragma unroll
        for (int rg = 0; rg < 4; rg++) {
          int rloc = wm * 64 + mt * 16 + q4 * 4 + rg;
          int dp = m0 + rloc;
          int c  = dp & 31;
          int j0 = (dp >> 5) & 7;
          int i0 = dp >> 8;
          int h = i0 * 32 + i1;
          int w = j0 * 32 + j1;
          if (h < 252 && w < 252)
            Ob[(((size_t)zz * 32 + c) * 252 + h) * 252 + w] =
                acc[mt][nt][rg] * svb[rloc];
        }
      }
    }
  }
}

// ---------------------------------------------------------------------------
// Kernel 5: row softmax over S (bf16, in place -> P). Block per row (b,l).
// ---------------------------------------------------------------------------
__global__ void softmax_kernel(unsigned short* __restrict__ S) {
  unsigned short* row = S + (size_t)blockIdx.x * 1024;
  int tid  = threadIdx.x;
  int lane = tid & 63;
  int wid  = tid >> 6;

  uint2 u = *(const uint2*)&row[tid * 4];
  float x0 = bf2f(u.x & 0xFFFF);
  float x1 = bf2f(u.x >> 16);
  float x2 = bf2f(u.y & 0xFFFF);
  float x3 = bf2f(u.y >> 16);

  __shared__ float red[8];
  float mx = fmaxf(fmaxf(x0, x1), fmaxf(x2, x3));
  #pragma unroll
  for (int off = 32; off > 0; off >>= 1) mx = fmaxf(mx, __shfl_down(mx, off));
  if (lane == 0) red[wid] = mx;
  __syncthreads();
  if (tid == 0)
    red[4] = fmaxf(fmaxf(red[0], red[1]), fmaxf(red[2], red[3]));
  __syncthreads();
  float bm = red[4];

  float e0 = __expf(x0 - bm), e1 = __expf(x1 - bm);
  float e2 = __expf(x2 - bm), e3 = __expf(x3 - bm);
  float s = e0 + e1 + e2 + e3;
  #pragma unroll
  for (int off = 32; off > 0; off >>= 1) s += __shfl_down(s, off);
  if (lane == 0) red[wid] = s;
  __syncthreads();
  if (tid == 0) red[5] = 1.0f / (red[0] + red[1] + red[2] + red[3]);
  __syncthreads();
  float inv = red[5];

  unsigned int o0 = f2bf(e0 * inv) | (f2bf(e1 * inv) << 16);
  unsigned int o1 = f2bf(e2 * inv) | (f2bf(e3 * inv) << 16);
  uint2 o; o.x = o0; o.y = o1;
  *(uint2*)&row[tid * 4] = o;
}

// ---------------------------------------------------------------------------
extern "C" void kernel_launch(void* const* d_in, const int* in_sizes, int n_in,
                              void* d_out, int out_size, void* d_ws, size_t ws_size,
                              hipStream_t stream) {
  const float* q = (const float*)d_in[0];
  const float* k = (const float*)d_in[1];
  const float* v = (const float*)d_in[2];
  float* out = (float*)d_out;

  char* ws = (char*)d_ws;
  float* sv = (float*)ws;                                       // 8*2048*4 = 64 KB
  unsigned short* Qh = (unsigned short*)(ws + 196608);          // 32 MB
  unsigned short* Kh = Qh + (size_t)8 * 1024 * 2048;            // 32 MB
  unsigned short* Vt = Kh + (size_t)8 * 1024 * 2048;            // 32 MB
  unsigned short* S  = Vt + (size_t)8 * 2048 * 1024;            // 16 MB

  const float SIM_SCALE = 0.02209708691207961f;  // 2048^-0.5

  hipMemsetAsync(sv, 0, (size_t)8 * 2048 * sizeof(float), stream);
  pack_qk_fused<<<512, 256, 0, stream>>>(q, k, Qh, Kh);
  pack_v_kernel<<<2048, 256, 0, stream>>>(v, Vt, sv);
  gemm_nt<0><<<512, 256, 0, stream>>>(
      Qh, Kh, 2048, 1024 * 2048, 1024 * 2048, (void*)S, SIM_SCALE, nullptr);
  softmax_kernel<<<8192, 256, 0, stream>>>(S);
  gemm_nt<1><<<1024, 256, 0, stream>>>(
      Vt, S, 1024, 2048 * 1024, 1024 * 1024, (void*)out, 1.0f, sv);
}

// Round 3
// 356.230 us; speedup vs baseline: 1.0625x; 1.0625x over previous
//
#include <hip/hip_runtime.h>
#include <cstdint>
#include <cstddef>

// ---------------------------------------------------------------------------
// cross_attention: b=8, c=32, 252x252, ws=8 -> padded 256x256.
// tokens l=(i1,j1) in 32x32, features d'=(i0*256 + j0*32 + c) in 2048.
// Pipeline (R8): pack_qk_fused (register-prefetch pipelined + dbuf LDS,
//   1 barrier/iter, raw s_barrier w/o vmcnt drain)  ->  pack_v (raw bf16 Vt
//   + fused svsum atomics)  ->  S = Qh Kh^T * 2048^-0.5 -> softmax ->
//   Ot = (rsqrt(svsum).*Vt) P^T fused scatter.
// R2 evidence: pack_qk was latency-bound (VALUBusy 9.5%, occ 20%, 2.44 TB/s,
// 8000 cy/iter vs ~1600 BW-bound) — HBM load sat on the critical path each
// iteration. Fix: issue i1+1's loads before the barrier, consume next iter.
// ---------------------------------------------------------------------------

typedef __bf16 bf16x8 __attribute__((ext_vector_type(8)));
typedef float  f32x4  __attribute__((ext_vector_type(4)));

__device__ __forceinline__ unsigned int f2bf(float f) {
  unsigned int u = __builtin_bit_cast(unsigned int, f);
  u += 0x7FFFu + ((u >> 16) & 1u);   // round-to-nearest-even
  return u >> 16;
}
__device__ __forceinline__ float bf2f(unsigned int h) {
  return __builtin_bit_cast(float, h << 16);
}

__device__ __forceinline__ void load_lds16(const void* g, void* l) {
  __builtin_amdgcn_global_load_lds(
      (const __attribute__((address_space(1))) void*)g,
      (__attribute__((address_space(3))) void*)l, 16, 0, 0);
}

// LDS-visibility-only barrier: waits local ds ops, does NOT drain vmcnt —
// keeps prefetch global loads and pack global stores in flight across it.
__device__ __forceinline__ void bar_lds() {
  asm volatile("s_waitcnt lgkmcnt(0)" ::: "memory");
  __builtin_amdgcn_s_barrier();
}

// ---------------------------------------------------------------------------
// Kernel 1: fused norm+pack for Q,K. Block = (t, b, i0, j0g): owns the
// 32c x 32h x 64w strip = windows (i0, j0g*2+{0,1}).
// Pipelined loop over i1: [stage regs->tf[p], accumulate squares] [prefetch
// row i1+1 -> regs] [bar_lds] [gather bf16 -> global]. One barrier/iter,
// HBM latency hidden behind the gather phase. Then reduce -> scales, and
// phase C rescales the block's own 1024x64 output region in place (L2-hot).
// Reflect pad by weights (247..250 x2, >=252 -> 0).
// ---------------------------------------------------------------------------
__global__ __launch_bounds__(256)
void pack_qk_fused(const float* __restrict__ q, const float* __restrict__ k,
                   unsigned short* __restrict__ Qh,
                   unsigned short* __restrict__ Kh) {
  int bx  = blockIdx.x;          // grid 512
  int t   = bx >> 8;             // 0..1
  int b   = (bx >> 5) & 7;
  int i0  = (bx >> 2) & 7;
  int j0g = bx & 3;
  const float* xb = (t ? k : q) + (size_t)b * 32 * 63504;

  __shared__ float tf[2][32 * 65];  // dbuf [c][pos 0..63], stride 65
  __shared__ float red[512];
  __shared__ float sclt[64];        // [c*2 + j0l]

  int tid = threadIdx.x;
  int ch  = tid & 15;              // 16B chunk within 64-w slice
  int c2  = tid >> 4;              // c = c2, c2+16

  int wbase = j0g * 64 + ch * 4;
  float we[4];
  #pragma unroll
  for (int e = 0; e < 4; e++) {
    int w = wbase + e;
    we[e] = (w >= 252) ? 0.f : (((unsigned)(w - 247) <= 3u) ? 2.f : 1.f);
  }
  bool tail = (wbase == 252);      // only j0g==3, ch==15

  float pa = 0.f, pb = 0.f;        // window sums for c2 / c2+16 (j0l fixed)
  unsigned short* X = (t ? Kh : Qh) + (size_t)b * 1024 * 2048;

  int gsub = tid & 7;              // gather: d' octet within 64
  int gj1  = tid >> 3;
  int gjl  = gsub >> 2;
  int gc0  = (gsub & 3) * 8;

  auto load_pair = [&](int i1, float4& v0, float4& v1) {
    int h  = i0 * 32 + i1;
    int hs = (h < 252) ? h : 502 - h;
    const float* rowp = xb + (size_t)hs * 252;
    const float* s0 = rowp + (size_t)c2 * 63504;
    const float* s1 = rowp + (size_t)(c2 + 16) * 63504;
    if (!tail) {
      v0 = *(const float4*)&s0[wbase];
      v1 = *(const float4*)&s1[wbase];
    } else {  // w 252..255 mirror to 250,249,248,247
      v0.x = s0[250]; v0.y = s0[249]; v0.z = s0[248]; v0.w = s0[247];
      v1.x = s1[250]; v1.y = s1[249]; v1.z = s1[248]; v1.w = s1[247];
    }
  };

  float4 va0, va1;
  load_pair(0, va0, va1);
  int p = 0;

  for (int i1 = 0; i1 < 32; i1++) {
    int h  = i0 * 32 + i1;
    float rw = (h >= 252) ? 0.f : (((unsigned)(h - 247) <= 3u) ? 2.f : 1.f);

    // stage regs -> tf[p], accumulate weighted squares
    {
      float s0 = rw * (we[0] * va0.x * va0.x + we[1] * va0.y * va0.y +
                       we[2] * va0.z * va0.z + we[3] * va0.w * va0.w);
      float s1 = rw * (we[0] * va1.x * va1.x + we[1] * va1.y * va1.y +
                       we[2] * va1.z * va1.z + we[3] * va1.w * va1.w);
      pa += s0; pb += s1;
      float* d0 = &tf[p][c2 * 65 + ch * 4];
      d0[0] = va0.x; d0[1] = va0.y; d0[2] = va0.z; d0[3] = va0.w;
      float* d1 = &tf[p][(c2 + 16) * 65 + ch * 4];
      d1[0] = va1.x; d1[1] = va1.y; d1[2] = va1.z; d1[3] = va1.w;
    }

    // prefetch next row into regs (in flight across the barrier; consumed
    // at the top of the next iteration)
    float4 vb0, vb1;
    if (i1 < 31) load_pair(i1 + 1, vb0, vb1);

    bar_lds();

    // gather bf16 uint4 -> Qh/Kh (128B contiguous lines fully owned)
    {
      int pos = gjl * 32 + gj1;
      unsigned int ov[4];
      #pragma unroll
      for (int m = 0; m < 4; m++) {
        unsigned int lo = f2bf(tf[p][(gc0 + 2 * m)     * 65 + pos]);
        unsigned int hi = f2bf(tf[p][(gc0 + 2 * m + 1) * 65 + pos]);
        ov[m] = lo | (hi << 16);
      }
      int l = i1 * 32 + gj1;
      uint4 o4; o4.x = ov[0]; o4.y = ov[1]; o4.z = ov[2]; o4.w = ov[3];
      *(uint4*)&X[(size_t)l * 2048 + i0 * 256 + j0g * 64 + gsub * 8] = o4;
    }

    p ^= 1;
    va0 = vb0; va1 = vb1;
  }

  // reduce partials -> 64 scales (full __syncthreads: also drains the pack
  // stores so phase C's read-back below is coherent)
  red[tid] = pa; red[256 + tid] = pb;
  __syncthreads();
  if (tid < 64) {
    int c = tid & 31, jl = tid >> 5;
    int base = (c & 15) * 16 + jl * 8 + ((c >= 16) ? 256 : 0);
    float s = 0.f;
    #pragma unroll
    for (int u = 0; u < 8; u++) s += red[base + u];
    sclt[c * 2 + jl] = 1.f / fmaxf(sqrtf(s), 1e-12f);
  }
  __syncthreads();

  // phase C: in-place scale of the block's 1024 x 64 d' region (L2-hot)
  {
    float sc[8];
    #pragma unroll
    for (int m = 0; m < 8; m++) sc[m] = sclt[(gc0 + m) * 2 + gjl];
    unsigned short* basep = &X[i0 * 256 + j0g * 64 + gsub * 8];
    int lb = tid >> 3;
    #pragma unroll 4
    for (int it = 0; it < 32; it++) {
      size_t off = (size_t)(it * 32 + lb) * 2048;
      uint4 u = *(uint4*)&basep[off];
      uint4 o;
      o.x = f2bf(bf2f(u.x & 0xFFFF) * sc[0]) | (f2bf(bf2f(u.x >> 16) * sc[1]) << 16);
      o.y = f2bf(bf2f(u.y & 0xFFFF) * sc[2]) | (f2bf(bf2f(u.y >> 16) * sc[3]) << 16);
      o.z = f2bf(bf2f(u.z & 0xFFFF) * sc[4]) | (f2bf(bf2f(u.z >> 16) * sc[5]) << 16);
      o.w = f2bf(bf2f(u.w & 0xFFFF) * sc[6]) | (f2bf(bf2f(u.w >> 16) * sc[7]) << 16);
      *(uint4*)&basep[off] = o;
    }
  }
}

// ---------------------------------------------------------------------------
// Kernel 2: pack V to bf16 Vt[d'][l] — RAW (scale folded into gemm2), no LDS.
// Fused: sum-of-squares per (b, d') row accumulated into svsum via 4-lane
// shfl reduce + one atomicAdd per (c, j0) per block. svsum zeroed via
// hipMemsetAsync before launch.
// ---------------------------------------------------------------------------
__global__ void pack_v_kernel(const float* __restrict__ v,
                              unsigned short* __restrict__ Vt,
                              float* __restrict__ svsum) {
  int bx = blockIdx.x;
  int b  = bx >> 8;
  int i0 = (bx >> 5) & 7;
  int i1 = bx & 31;
  int h  = i0 * 32 + i1;
  int hs = (h < 252) ? h : 502 - h;
  const float* src = v + (size_t)b * 32 * 63504 + (size_t)hs * 252;
  unsigned short* dst = Vt + (size_t)b * 2048 * 1024
                           + (size_t)(i0 * 256) * 1024 + i1 * 32;

  int tid = threadIdx.x;
  int j1c = tid & 3;
  int c   = (tid >> 2) & 31;
  int j0g = tid >> 7;          // 0..1
  const float* s = src + (size_t)c * 63504;

  float psum[4];

  #pragma unroll
  for (int jj = 0; jj < 4; jj++) {
    int j0 = j0g * 4 + jj;
    int w0 = j0 * 32 + j1c * 8;
    float f0, f1, f2, f3, f4, f5, f6, f7;
    if (w0 + 8 <= 252) {
      float4 a = *(const float4*)&s[w0];
      float4 bq = *(const float4*)&s[w0 + 4];
      f0 = a.x; f1 = a.y; f2 = a.z; f3 = a.w;
      f4 = bq.x; f5 = bq.y; f6 = bq.z; f7 = bq.w;
    } else {  // w0==248: cols 248..255 -> 248,249,250,251,250,249,248,247
      float4 a = *(const float4*)&s[244];
      float4 bq = *(const float4*)&s[248];
      f0 = bq.x; f1 = bq.y; f2 = bq.z; f3 = bq.w;
      f4 = bq.z; f5 = bq.y; f6 = bq.x; f7 = a.w;
    }
    psum[jj] = f0*f0 + f1*f1 + f2*f2 + f3*f3 + f4*f4 + f5*f5 + f6*f6 + f7*f7;
    uint4 o;
    o.x = f2bf(f0) | (f2bf(f1) << 16);
    o.y = f2bf(f2) | (f2bf(f3) << 16);
    o.z = f2bf(f4) | (f2bf(f5) << 16);
    o.w = f2bf(f6) | (f2bf(f7) << 16);
    *(uint4*)&dst[(size_t)(j0 * 32 + c) * 1024 + j1c * 8] = o;
  }

  #pragma unroll
  for (int jj = 0; jj < 4; jj++) {
    float ssum = psum[jj];
    ssum += __shfl_down(ssum, 2, 4);
    ssum += __shfl_down(ssum, 1, 4);
    if (j1c == 0) {
      int j0 = j0g * 4 + jj;
      atomicAdd(&svsum[(size_t)b * 2048 + i0 * 256 + j0 * 32 + c], ssum);
    }
  }
}

// ---------------------------------------------------------------------------
// GEMM NT: C[M][N] = A[M][K] * B[N][K]^T, bf16 in, fp32 acc.
// 1D grid, decode: b = flat&7 (XCD affinity), m, n of the remainder.
// MODE 0: store bf16 S * scale.  MODE 1: acc *= rsqrt(svsum[row]), scatter
// fp32 + crop.
// ---------------------------------------------------------------------------
template <int MODE>
__global__ __launch_bounds__(256, 4)
void gemm_nt(const unsigned short* __restrict__ A,
             const unsigned short* __restrict__ B,
             int K, int Asb, int Bsb, void* __restrict__ Cout, float scale,
             const float* __restrict__ sv) {
  __shared__ unsigned short lA[128 * 64];
  __shared__ unsigned short lB[128 * 64];
  __shared__ float svb[(MODE == 1) ? 128 : 1];

  const int flat = blockIdx.x;
  const int zz   = flat & 7;
  const int rr   = flat >> 3;
  const int my   = rr >> 3;
  const int nx   = rr & 7;

  const int tid  = threadIdx.x;
  const int lane = tid & 63;
  const int wave = tid >> 6;
  const int ln15 = lane & 15;
  const int q4   = lane >> 4;
  const int wm   = wave >> 1;
  const int wn   = wave & 1;
  const int m0   = my * 128;
  const int n0   = nx * 128;
  const unsigned short* Ab = A + (size_t)zz * Asb;
  const unsigned short* Bb = B + (size_t)zz * Bsb;

  if (MODE == 1 && tid < 128)
    svb[tid] = 1.f / fmaxf(sqrtf(sv[(size_t)zz * 2048 + m0 + tid]), 1e-12f);

  const int srow = lane >> 3;
  const int kcp  = lane & 7;
  const int kcl  = kcp ^ srow;      // xor-swizzled source chunk

  f32x4 acc[4][4] = {};

  for (int k0 = 0; k0 < K; k0 += 64) {
    #pragma unroll
    for (int r = 0; r < 4; r++) {
      int rowg = wave * 32 + r * 8;
      int row  = rowg + srow;
      load_lds16(&Ab[(size_t)(m0 + row) * K + k0 + kcl * 8], &lA[rowg * 64]);
      load_lds16(&Bb[(size_t)(n0 + row) * K + k0 + kcl * 8], &lB[rowg * 64]);
    }
    __syncthreads();
    #pragma unroll
    for (int kk = 0; kk < 2; kk++) {
      bf16x8 af[4], bfr[4];
      #pragma unroll
      for (int mt = 0; mt < 4; mt++) {
        int row = wm * 64 + mt * 16 + ln15;
        int pc  = (kk * 4 + q4) ^ (row & 7);
        af[mt] = *(const bf16x8*)&lA[row * 64 + pc * 8];
      }
      #pragma unroll
      for (int nt = 0; nt < 4; nt++) {
        int row = wn * 64 + nt * 16 + ln15;
        int pc  = (kk * 4 + q4) ^ (row & 7);
        bfr[nt] = *(const bf16x8*)&lB[row * 64 + pc * 8];
      }
      #pragma unroll
      for (int mt = 0; mt < 4; mt++)
        #pragma unroll
        for (int nt = 0; nt < 4; nt++)
          acc[mt][nt] = __builtin_amdgcn_mfma_f32_16x16x32_bf16(
              af[mt], bfr[nt], acc[mt][nt], 0, 0, 0);
    }
    __syncthreads();
  }

  if (MODE == 0) {
    unsigned short* Sb = (unsigned short*)Cout + (size_t)zz * 1024 * 1024;
    #pragma unroll
    for (int mt = 0; mt < 4; mt++) {
      #pragma unroll
      for (int nt = 0; nt < 4; nt++) {
        int col = n0 + wn * 64 + nt * 16 + ln15;
        #pragma unroll
        for (int rg = 0; rg < 4; rg++) {
          int rowi = m0 + wm * 64 + mt * 16 + q4 * 4 + rg;
          Sb[(size_t)rowi * 1024 + col] = (unsigned short)f2bf(acc[mt][nt][rg] * scale);
        }
      }
    }
  } else {
    float* Ob = (float*)Cout;
    #pragma unroll
    for (int mt = 0; mt < 4; mt++) {
      #pragma unroll
      for (int nt = 0; nt < 4; nt++) {
        int l  = n0 + wn * 64 + nt * 16 + ln15;
        int i1 = l >> 5, j1 = l & 31;
        #pragma unroll
        for (int rg = 0; rg < 4; rg++) {
          int rloc = wm * 64 + mt * 16 + q4 * 4 + rg;
          int dp = m0 + rloc;
          int c  = dp & 31;
          int j0 = (dp >> 5) & 7;
          int i0 = dp >> 8;
          int h = i0 * 32 + i1;
          int w = j0 * 32 + j1;
          if (h < 252 && w < 252)
            Ob[(((size_t)zz * 32 + c) * 252 + h) * 252 + w] =
                acc[mt][nt][rg] * svb[rloc];
        }
      }
    }
  }
}

// ---------------------------------------------------------------------------
// Kernel 5: row softmax over S (bf16, in place -> P). Block per row (b,l).
// ---------------------------------------------------------------------------
__global__ void softmax_kernel(unsigned short* __restrict__ S) {
  unsigned short* row = S + (size_t)blockIdx.x * 1024;
  int tid  = threadIdx.x;
  int lane = tid & 63;
  int wid  = tid >> 6;

  uint2 u = *(const uint2*)&row[tid * 4];
  float x0 = bf2f(u.x & 0xFFFF);
  float x1 = bf2f(u.x >> 16);
  float x2 = bf2f(u.y & 0xFFFF);
  float x3 = bf2f(u.y >> 16);

  __shared__ float red[8];
  float mx = fmaxf(fmaxf(x0, x1), fmaxf(x2, x3));
  #pragma unroll
  for (int off = 32; off > 0; off >>= 1) mx = fmaxf(mx, __shfl_down(mx, off));
  if (lane == 0) red[wid] = mx;
  __syncthreads();
  if (tid == 0)
    red[4] = fmaxf(fmaxf(red[0], red[1]), fmaxf(red[2], red[3]));
  __syncthreads();
  float bm = red[4];

  float e0 = __expf(x0 - bm), e1 = __expf(x1 - bm);
  float e2 = __expf(x2 - bm), e3 = __expf(x3 - bm);
  float s = e0 + e1 + e2 + e3;
  #pragma unroll
  for (int off = 32; off > 0; off >>= 1) s += __shfl_down(s, off);
  if (lane == 0) red[wid] = s;
  __syncthreads();
  if (tid == 0) red[5] = 1.0f / (red[0] + red[1] + red[2] + red[3]);
  __syncthreads();
  float inv = red[5];

  unsigned int o0 = f2bf(e0 * inv) | (f2bf(e1 * inv) << 16);
  unsigned int o1 = f2bf(e2 * inv) | (f2bf(e3 * inv) << 16);
  uint2 o; o.x = o0; o.y = o1;
  *(uint2*)&row[tid * 4] = o;
}

// ---------------------------------------------------------------------------
extern "C" void kernel_launch(void* const* d_in, const int* in_sizes, int n_in,
                              void* d_out, int out_size, void* d_ws, size_t ws_size,
                              hipStream_t stream) {
  const float* q = (const float*)d_in[0];
  const float* k = (const float*)d_in[1];
  const float* v = (const float*)d_in[2];
  float* out = (float*)d_out;

  char* ws = (char*)d_ws;
  float* sv = (float*)ws;                                       // 8*2048*4 = 64 KB
  unsigned short* Qh = (unsigned short*)(ws + 196608);          // 32 MB
  unsigned short* Kh = Qh + (size_t)8 * 1024 * 2048;            // 32 MB
  unsigned short* Vt = Kh + (size_t)8 * 1024 * 2048;            // 32 MB
  unsigned short* S  = Vt + (size_t)8 * 2048 * 1024;            // 16 MB

  const float SIM_SCALE = 0.02209708691207961f;  // 2048^-0.5

  hipMemsetAsync(sv, 0, (size_t)8 * 2048 * sizeof(float), stream);
  pack_qk_fused<<<512, 256, 0, stream>>>(q, k, Qh, Kh);
  pack_v_kernel<<<2048, 256, 0, stream>>>(v, Vt, sv);
  gemm_nt<0><<<512, 256, 0, stream>>>(
      Qh, Kh, 2048, 1024 * 2048, 1024 * 2048, (void*)S, SIM_SCALE, nullptr);
  softmax_kernel<<<8192, 256, 0, stream>>>(S);
  gemm_nt<1><<<1024, 256, 0, stream>>>(
      Vt, S, 1024, 2048 * 1024, 1024 * 1024, (void*)out, 1.0f, sv);
}